// Round 7
// baseline (112.931 us; speedup 1.0000x reference)
//
#include <hip/hip_runtime.h>

// QConv2d v11: fused single kernel (v6b structure — proven correct, steady 45.4us)
// with DOUBLED store-side occupancy: TPB 512 -> 1024 (16 waves/CU, 1 block/CU).
// Evidence: store BW scales with resident waves (8w->1.6, 16w->4.2, 32w->6.2 TB/s);
// v6b's 45us ~= 67MB write at 1.6 TB/s with 8 waves. Two-kernel splits (v9/v10)
// regressed in steady state (stage1 only 4 waves/CU, HBM-cold rho, extra launch).
// Here: producers = waves 0-3 (identical wave-private pipeline, X[64] in regs);
// epilogue re-divided over 1024 threads = 16q x 16spl x 4c, cs looped — same
// addresses/coalescing as v6b, 2x the storing waves. launch_bounds(1024,1) keeps
// the proven 128-VGPR budget (4 waves/SIMD x 108 = 432 <= 512; LDS 69.6KB, 1 blk/CU).

#define TPB 1024

typedef float nfloat4 __attribute__((ext_vector_type(4)));

__global__ __launch_bounds__(TPB, 1) void qconv_fused(
    const float* __restrict__ rho,   // [256][128][128]
    const float* __restrict__ ux,    // [8][8]
    const float* __restrict__ uy,    // [8][8]
    const float* __restrict__ uc,    // [4][4]
    float* __restrict__ out)         // [256][256][256]
{
    __shared__ alignas(16) float L[4][64][68];  // 69632 B

    const int tid  = threadIdx.x;
    const int b    = blockIdx.x;
    const int w    = tid >> 6;
    const int lane = tid & 63;
    const int pyp  = lane >> 3, qyp = lane & 7;   // producer post-transpose identity

    // epilogue work identity: 1024 = 16 q x 16 spl x 4 c (cs looped 0..3)
    const int qg   = tid & 15;
    const int spl  = (tid >> 4) & 15;
    const int cblk = tid >> 8;                    // 0..3

    float e0[4], e1[4];
#pragma unroll
    for (int c = 0; c < 4; ++c) { e0[c] = uc[c*4+2]; e1[c] = uc[c*4+3]; }
    float* ob = out + (size_t)b * 65536;

    float X[64];  // producer in-place state; live through strips (waves 0-3 only)

    if (w < 4) {  // producer waves
        const int c1 = w >> 1, c2 = w & 1;
        const int px = lane >> 3, qx = lane & 7;
        const float* rb = rho + (size_t)b * 16384
                        + (size_t)((c1 << 6) + (px << 3)) * 128 + (c2 << 6) + (qx << 3);

        // load X[py][qy]: 16 x b128
#pragma unroll
        for (int py = 0; py < 8; ++py) {
            float4 lo = *(const float4*)(rb + py * 128);
            float4 hi = *(const float4*)(rb + py * 128 + 4);
            X[py*8+0]=lo.x; X[py*8+1]=lo.y; X[py*8+2]=lo.z; X[py*8+3]=lo.w;
            X[py*8+4]=hi.x; X[py*8+5]=hi.y; X[py*8+6]=hi.z; X[py*8+7]=hi.w;
        }

        // Stage A: contract qy (row-local, in-place)
#pragma unroll
        for (int r = 0; r < 8; ++r) {
            float t[8];
#pragma unroll
            for (int j = 0; j < 8; ++j) {
                float a = 0.f;
#pragma unroll
                for (int k = 0; k < 8; ++k) a += uy[j*8+k] * X[r*8+k];
                t[j] = a;
            }
#pragma unroll
            for (int j = 0; j < 8; ++j) X[r*8+j] = t[j];
        }

        // Stage B: contract py (col-local, in-place)
#pragma unroll
        for (int cc = 0; cc < 8; ++cc) {
            float t[8];
#pragma unroll
            for (int i = 0; i < 8; ++i) {
                float a = 0.f;
#pragma unroll
                for (int k = 0; k < 8; ++k) a += uy[i*8+k] * X[k*8+cc];
                t[i] = a;
            }
#pragma unroll
            for (int i = 0; i < 8; ++i) X[i*8+cc] = t[i];
        }

        // wave-private 64x64 transpose via LDS slice w, XOR-swizzled columns
        // (row stride 68 == 4 mod 32; swizzle -> conflict-free b128 reads).
#pragma unroll
        for (int e = 0; e < 64; ++e)
            L[w][e][lane ^ (((e >> 3) & 7) << 2)] = X[e];
        __asm__ volatile("s_waitcnt lgkmcnt(0)" ::: "memory");  // DS in-order per wave
        {
            const int sw = ((lane >> 3) & 7) << 2;
#pragma unroll
            for (int f4 = 0; f4 < 16; ++f4) {
                float4 v = *(const float4*)&L[w][lane][(f4 * 4) ^ sw];
                X[f4*4+0]=v.x; X[f4*4+1]=v.y; X[f4*4+2]=v.z; X[f4*4+3]=v.w;
            }
        }

        // Stage C: contract qx (row-local, in-place)
#pragma unroll
        for (int p = 0; p < 8; ++p) {
            float t[8];
#pragma unroll
            for (int j = 0; j < 8; ++j) {
                float a = 0.f;
#pragma unroll
                for (int k = 0; k < 8; ++k) a += ux[j*8+k] * X[p*8+k];
                t[j] = a;
            }
#pragma unroll
            for (int j = 0; j < 8; ++j) X[p*8+j] = t[j];
        }
    }

    // strip loop: producers finish W rows 2s,2s+1 (Stage D); one lgkm-only
    // barrier per strip; stores never vmcnt-drained in-loop. Strip s+1's LDS
    // writes hit rows [16(s+1),16(s+1)+16) — disjoint from strip-s reads.
#pragma unroll
    for (int s = 0; s < 4; ++s) {
        if (w < 4) {
#pragma unroll
            for (int i2 = 0; i2 < 2; ++i2) {
                const int i = 2*s + i2;   // px'
#pragma unroll
                for (int j = 0; j < 8; ++j) {
                    float acc = 0.f;
#pragma unroll
                    for (int k = 0; k < 8; ++k) acc += ux[i*8+k] * X[k*8+j];
                    L[w][i*8+pyp][j*8+qyp] = acc;   // plain (unswizzled) W region
                }
            }
        }
        // LDS-visibility barrier only: lgkmcnt(0) + raw s_barrier (no vmcnt drain;
        // asm "memory" fences pin LDS ops to their side, rule #18).
        __asm__ volatile("s_waitcnt lgkmcnt(0)" ::: "memory");
        __builtin_amdgcn_s_barrier();
        __asm__ volatile("" ::: "memory");

        const int sp = 16*s + spl;
        float4 wv[4];
#pragma unroll
        for (int ww = 0; ww < 4; ++ww) wv[ww] = *(const float4*)&L[ww][sp][qg * 4];

        float* obp = ob + (size_t)(cblk * 64 + sp) * 256 + qg * 4;
#pragma unroll
        for (int cs = 0; cs < 4; ++cs) {
            const float k00 = e0[cblk]*e0[cs], k01 = e0[cblk]*e1[cs];
            const float k10 = e1[cblk]*e0[cs], k11 = e1[cblk]*e1[cs];
            nfloat4 v;
            v.x = k00*wv[0].x + k01*wv[1].x + k10*wv[2].x + k11*wv[3].x;
            v.y = k00*wv[0].y + k01*wv[1].y + k10*wv[2].y + k11*wv[3].y;
            v.z = k00*wv[0].z + k01*wv[1].z + k10*wv[2].z + k11*wv[3].z;
            v.w = k00*wv[0].w + k01*wv[1].w + k10*wv[2].w + k11*wv[3].w;
            __builtin_nontemporal_store(v, (nfloat4*)(obp + cs * 64));
        }
    }
}

extern "C" void kernel_launch(void* const* d_in, const int* in_sizes, int n_in,
                              void* d_out, int out_size, void* d_ws, size_t ws_size,
                              hipStream_t stream) {
    const float* rho = (const float*)d_in[0];
    const float* ux  = (const float*)d_in[1];
    const float* uy  = (const float*)d_in[2];
    const float* uc  = (const float*)d_in[3];
    float* out = (float*)d_out;
    qconv_fused<<<dim3(256), dim3(TPB), 0, stream>>>(rho, ux, uy, uc, out);
}

// Round 8
// 95.276 us; speedup vs baseline: 1.1853x; 1.1853x over previous
//
#include <hip/hip_runtime.h>

// QConv2d v12: v6b with the strip pipeline COLLAPSED into one dense store phase.
// Evidence: poison fill sustains 6.2 TB/s at ~8% occupancy (~2.7 waves/CU) =>
// write BW needs dense store issue, not more waves. v6b chopped its 256KB/block
// of stores into 8-instr bursts between barriers/LDS reads -> 1.6 TB/s. Here:
// producers (waves 0-3, proven v6b pipeline, VGPR 108 no spill) compute ALL of
// W into LDS; ONE lgkm-only barrier; then all 512 threads preload their 16
// float4s of W and issue 32 nontemporal stores back-to-back, fill-style (X[64]
// is dead by then, so peak VGPR unchanged). Grid 256, TPB 512, bounds (512,2) —
// the only config that never spilled. d_ws untouched.

#define TPB 512

typedef float nfloat4 __attribute__((ext_vector_type(4)));

__global__ __launch_bounds__(TPB, 2) void qconv_fused(
    const float* __restrict__ rho,   // [256][128][128]
    const float* __restrict__ ux,    // [8][8]
    const float* __restrict__ uy,    // [8][8]
    const float* __restrict__ uc,    // [4][4]
    float* __restrict__ out)         // [256][256][256]
{
    __shared__ alignas(16) float L[4][64][68];  // 69632 B; full W for all 4 quads

    const int tid  = threadIdx.x;
    const int b    = blockIdx.x;
    const int w    = tid >> 6;
    const int lane = tid & 63;
    const int pyp  = lane >> 3, qyp = lane & 7;   // producer post-transpose identity

    // store-phase work identity: 512 = 16 qg x 2 csh x 16 spl; per thread
    // sp in {spl,16+spl,32+spl,48+spl}, c 0..3, cs in {2csh,2csh+1} -> 32 float4s
    const int qg  = tid & 15;
    const int csh = (tid >> 4) & 1;
    const int spl = tid >> 5;                     // 0..15

    float e0[4], e1[4];
#pragma unroll
    for (int c = 0; c < 4; ++c) { e0[c] = uc[c*4+2]; e1[c] = uc[c*4+3]; }
    float* ob = out + (size_t)b * 65536;

    if (w < 4) {  // producer waves (proven v6b pipeline)
        float X[64];
        const int c1 = w >> 1, c2 = w & 1;
        const int px = lane >> 3, qx = lane & 7;
        const float* rb = rho + (size_t)b * 16384
                        + (size_t)((c1 << 6) + (px << 3)) * 128 + (c2 << 6) + (qx << 3);

        // load X[py][qy]: 16 x b128
#pragma unroll
        for (int py = 0; py < 8; ++py) {
            float4 lo = *(const float4*)(rb + py * 128);
            float4 hi = *(const float4*)(rb + py * 128 + 4);
            X[py*8+0]=lo.x; X[py*8+1]=lo.y; X[py*8+2]=lo.z; X[py*8+3]=lo.w;
            X[py*8+4]=hi.x; X[py*8+5]=hi.y; X[py*8+6]=hi.z; X[py*8+7]=hi.w;
        }

        // Stage A: contract qy (row-local, in-place)
#pragma unroll
        for (int r = 0; r < 8; ++r) {
            float t[8];
#pragma unroll
            for (int j = 0; j < 8; ++j) {
                float a = 0.f;
#pragma unroll
                for (int k = 0; k < 8; ++k) a += uy[j*8+k] * X[r*8+k];
                t[j] = a;
            }
#pragma unroll
            for (int j = 0; j < 8; ++j) X[r*8+j] = t[j];
        }

        // Stage B: contract py (col-local, in-place)
#pragma unroll
        for (int cc = 0; cc < 8; ++cc) {
            float t[8];
#pragma unroll
            for (int i = 0; i < 8; ++i) {
                float a = 0.f;
#pragma unroll
                for (int k = 0; k < 8; ++k) a += uy[i*8+k] * X[k*8+cc];
                t[i] = a;
            }
#pragma unroll
            for (int i = 0; i < 8; ++i) X[i*8+cc] = t[i];
        }

        // wave-private 64x64 transpose via LDS slice w, XOR-swizzled columns
        // (row stride 68 == 4 mod 32; swizzle -> conflict-free b128 reads).
#pragma unroll
        for (int e = 0; e < 64; ++e)
            L[w][e][lane ^ (((e >> 3) & 7) << 2)] = X[e];
        __asm__ volatile("s_waitcnt lgkmcnt(0)" ::: "memory");  // DS in-order per wave
        {
            const int sw = ((lane >> 3) & 7) << 2;
#pragma unroll
            for (int f4 = 0; f4 < 16; ++f4) {
                float4 v = *(const float4*)&L[w][lane][(f4 * 4) ^ sw];
                X[f4*4+0]=v.x; X[f4*4+1]=v.y; X[f4*4+2]=v.z; X[f4*4+3]=v.w;
            }
        }

        // Stage C: contract qx (row-local, in-place)
#pragma unroll
        for (int p = 0; p < 8; ++p) {
            float t[8];
#pragma unroll
            for (int j = 0; j < 8; ++j) {
                float a = 0.f;
#pragma unroll
                for (int k = 0; k < 8; ++k) a += ux[j*8+k] * X[p*8+k];
                t[j] = a;
            }
#pragma unroll
            for (int j = 0; j < 8; ++j) X[p*8+j] = t[j];
        }

        // Stage D: contract px — ALL 8 output rows i; write full W to LDS.
        // (v6b did 2 rows per strip; collapsing removes 3 barriers and makes the
        //  store phase one dense run.)  <=2-way banks on writes: free.
#pragma unroll
        for (int i = 0; i < 8; ++i) {
#pragma unroll
            for (int j = 0; j < 8; ++j) {
                float acc = 0.f;
#pragma unroll
                for (int k = 0; k < 8; ++k) acc += ux[i*8+k] * X[k*8+j];
                L[w][i*8+pyp][j*8+qyp] = acc;
            }
        }
    }

    // ONE LDS-visibility barrier: lgkmcnt(0) + raw s_barrier (no vmcnt drain;
    // asm "memory" fences pin LDS ops to their side, rule #18).
    __asm__ volatile("s_waitcnt lgkmcnt(0)" ::: "memory");
    __builtin_amdgcn_s_barrier();
    __asm__ volatile("" ::: "memory");

    // Preload all 16 W float4s (X dead -> VGPR headroom), then 32 dense nt stores.
    float4 wv[4][4];  // [s][quad]
#pragma unroll
    for (int s = 0; s < 4; ++s)
#pragma unroll
        for (int ww = 0; ww < 4; ++ww)
            wv[s][ww] = *(const float4*)&L[ww][16*s + spl][qg * 4];

    // fill-style dense store run: no barriers, no LDS ops between stores
#pragma unroll
    for (int c = 0; c < 4; ++c) {
#pragma unroll
        for (int cs2 = 0; cs2 < 2; ++cs2) {
            const int cs = 2*csh + cs2;
            const float k00 = e0[c]*e0[cs], k01 = e0[c]*e1[cs];
            const float k10 = e1[c]*e0[cs], k11 = e1[c]*e1[cs];
#pragma unroll
            for (int s = 0; s < 4; ++s) {
                const int sp = 16*s + spl;
                nfloat4 v;
                v.x = k00*wv[s][0].x + k01*wv[s][1].x + k10*wv[s][2].x + k11*wv[s][3].x;
                v.y = k00*wv[s][0].y + k01*wv[s][1].y + k10*wv[s][2].y + k11*wv[s][3].y;
                v.z = k00*wv[s][0].z + k01*wv[s][1].z + k10*wv[s][2].z + k11*wv[s][3].z;
                v.w = k00*wv[s][0].w + k01*wv[s][1].w + k10*wv[s][2].w + k11*wv[s][3].w;
                __builtin_nontemporal_store(v,
                    (nfloat4*)&ob[(size_t)((c*64 + sp) * 256 + cs*64 + qg*4)]);
            }
        }
    }
}

extern "C" void kernel_launch(void* const* d_in, const int* in_sizes, int n_in,
                              void* d_out, int out_size, void* d_ws, size_t ws_size,
                              hipStream_t stream) {
    const float* rho = (const float*)d_in[0];
    const float* ux  = (const float*)d_in[1];
    const float* uy  = (const float*)d_in[2];
    const float* uc  = (const float*)d_in[3];
    float* out = (float*)d_out;
    qconv_fused<<<dim3(256), dim3(TPB), 0, stream>>>(rho, ux, uy, uc, out);
}